// Round 2
// baseline (93.825 us; speedup 1.0000x reference)
//
#include <hip/hip_runtime.h>

// out[b] = P @ X[b] @ P^T where P (7140x1024) is 0/1 with exactly one 1 per
// column => pure scatter: out[b][r(i)][r(j)] = X[b][i][j], zeros elsewhere.
// Row-oriented: zero rows (86%) are a bare store loop (memset-speed);
// data rows stage the 4KB source row in LDS and gather from LDS.

constexpr int D_IN   = 1024;
constexpr int D_OUT  = 7140;          // C(36,3)
constexpr int VROW   = D_OUT / 4;     // 1785 float4 per output row
constexpr int NQ     = 36;
constexpr int NROWS  = 2 * D_OUT;     // batch=2

__global__ __launch_bounds__(256) void sandwich_rows_kernel(
    const float* __restrict__ in, float* __restrict__ out)
{
    __shared__ __align__(16) short inv[D_OUT];   // out row/col -> in idx, or -1
    __shared__ __align__(16) float srow[D_IN];   // staged source row

    // Build inverse LUT (amortized over ~NROWS/gridDim rows per block)
    for (int t = threadIdx.x; t < D_OUT; t += blockDim.x) inv[t] = -1;
    __syncthreads();
    for (int t = threadIdx.x; t < D_IN; t += blockDim.x) {
        int ch   = t & 3;
        int col  = (t >> 2) & 15;
        int line = t >> 6;
        int a = line, b = 16 + col, c = 32 + ch;
        int r = 0;
        for (int x = 0; x < a; ++x) r += (NQ - 1 - x) * (NQ - 2 - x) / 2;
        for (int y = a + 1; y < b; ++y) r += NQ - 1 - y;
        r += c - b - 1;
        inv[r] = (short)t;
    }
    __syncthreads();

    for (int row = blockIdx.x; row < NROWS; row += gridDim.x) {
        int o = row, bb = 0;
        if (o >= D_OUT) { o -= D_OUT; bb = 1; }

        float4* __restrict__ orow = reinterpret_cast<float4*>(out) + (size_t)row * VROW;
        int io = inv[o];                       // block-uniform

        if (io < 0) {
            // zero row: pure store loop, memset-shaped
            const float4 z = make_float4(0.f, 0.f, 0.f, 0.f);
            for (int p = threadIdx.x; p < VROW; p += blockDim.x) orow[p] = z;
        } else {
            // data row: stage 1024-float source row into LDS (coalesced), gather from LDS
            const float4* __restrict__ srcv = reinterpret_cast<const float4*>(
                in + (size_t)bb * (D_IN * D_IN) + (size_t)io * D_IN);
            if (threadIdx.x < D_IN / 4)
                reinterpret_cast<float4*>(srow)[threadIdx.x] = srcv[threadIdx.x];
            __syncthreads();

            for (int p = threadIdx.x; p < VROW; p += blockDim.x) {
                short4 iv = *reinterpret_cast<const short4*>(&inv[p * 4]);
                float4 v;
                v.x = (iv.x >= 0) ? srow[iv.x] : 0.f;
                v.y = (iv.y >= 0) ? srow[iv.y] : 0.f;
                v.z = (iv.z >= 0) ? srow[iv.z] : 0.f;
                v.w = (iv.w >= 0) ? srow[iv.w] : 0.f;
                orow[p] = v;
            }
            __syncthreads();   // srow reused next row (block-uniform branch, safe)
        }
    }
}

extern "C" void kernel_launch(void* const* d_in, const int* in_sizes, int n_in,
                              void* d_out, int out_size, void* d_ws, size_t ws_size,
                              hipStream_t stream) {
    const float* in = (const float*)d_in[0];   // (2, 1024, 1024) f32
    float* out = (float*)d_out;                // (2, 7140, 7140) f32

    dim3 grid(2048), block(256);
    hipLaunchKernelGGL(sandwich_rows_kernel, grid, block, 0, stream, in, out);
}